// Round 1
// baseline (5102.078 us; speedup 1.0000x reference)
//
#include <hip/hip_runtime.h>

#define N_NODES 50000
#define N_EDGES 800000
#define NUM_MOL 2000

// ---------------------------------------------------------------------------
// Precompute type tables:
//   T1[t,c]  = atom_table[t,:] @ Wi[0:128,c]            (119x128)
//   T2c[a,c] = bond_table[a,:] @ Wi[128:192,c] + bi[c]  (4x128)
//   U1[t,c]  = atom_table[t,:] @ Wu1[0:128,c]           (119x128)
//   U2c[a,c] = bond_table[a,:] @ Wu1[128:192,c] + bu1[c](4x128)
// grid 123 blocks x 128 threads
// ---------------------------------------------------------------------------
__global__ void k_tables(const float* __restrict__ atom_table,
                         const float* __restrict__ bond_table,
                         const float* __restrict__ Wi,
                         const float* __restrict__ bi,
                         const float* __restrict__ Wu1,
                         const float* __restrict__ bu1,
                         float* __restrict__ T1, float* __restrict__ U1,
                         float* __restrict__ T2c, float* __restrict__ U2c) {
  int b = blockIdx.x;
  int c = threadIdx.x;
  if (b < 119) {
    float t = 0.f, u = 0.f;
    for (int k = 0; k < 128; k++) {
      float a = atom_table[b * 128 + k];
      t += a * Wi[k * 128 + c];
      u += a * Wu1[k * 128 + c];
    }
    T1[b * 128 + c] = t;
    U1[b * 128 + c] = u;
  } else {
    int a = b - 119;
    float t = bi[c], u = bu1[c];
    for (int k = 0; k < 64; k++) {
      float bv = bond_table[a * 64 + k];
      t += bv * Wi[(128 + k) * 128 + c];
      u += bv * Wu1[(128 + k) * 128 + c];
    }
    T2c[a * 128 + c] = t;
    U2c[a * 128 + c] = u;
  }
}

// ---------------------------------------------------------------------------
// Initial message scatter: agg[dst] += relu(T1[x[src]] + T2c[attr])
// one wave per edge; lane handles 2 channels. grid = E/4 blocks x 256
// ---------------------------------------------------------------------------
__global__ void k_scatter0(const int* __restrict__ x,
                           const int* __restrict__ eidx,
                           const int* __restrict__ attr,
                           const float* __restrict__ T1,
                           const float* __restrict__ T2c,
                           float* __restrict__ agg) {
  int e = blockIdx.x * 4 + (threadIdx.x >> 6);
  int lane = threadIdx.x & 63;
  int s = eidx[e];
  int d = eidx[N_EDGES + e];
  int a = attr[e];
  int xs = x[s];
  int c = lane * 2;
  float v0 = T1[xs * 128 + c]     + T2c[a * 128 + c];
  float v1 = T1[xs * 128 + c + 1] + T2c[a * 128 + c + 1];
  v0 = v0 > 0.f ? v0 : 0.f;
  v1 = v1 > 0.f ? v1 : 0.f;
  atomicAdd(&agg[d * 128 + c], v0);
  atomicAdd(&agg[d * 128 + c + 1], v1);
}

// ---------------------------------------------------------------------------
// aggW = agg @ Wu1[192:320, :]   (N x 128) @ (128 x 128)
// Persistent: each thread owns one output column, Wu1_b column in registers.
// block 128 threads, grid-stride over nodes.
// ---------------------------------------------------------------------------
__global__ __launch_bounds__(128) void k_aggW(const float* __restrict__ agg,
                                              const float* __restrict__ Wu1,
                                              float* __restrict__ aggW) {
  int c = threadIdx.x;
  float w[128];
#pragma unroll
  for (int k = 0; k < 128; k++) w[k] = Wu1[(192 + k) * 128 + c];
  __shared__ float as[128];
  for (int n = blockIdx.x; n < N_NODES; n += gridDim.x) {
    __syncthreads();
    as[c] = agg[n * 128 + c];
    __syncthreads();
    float acc = 0.f;
#pragma unroll
    for (int k = 0; k < 128; k += 4) {
      float4 a4 = *(const float4*)&as[k];
      acc += a4.x * w[k] + a4.y * w[k + 1] + a4.z * w[k + 2] + a4.w * w[k + 3];
    }
    aggW[n * 128 + c] = acc;
  }
}

// ---------------------------------------------------------------------------
// M[n*4+a, :] = relu( relu(U1[x[n]] + U2c[a] + aggW[n]) @ Wu2 + bu2 )
// Persistent; Wu2 column in registers; h broadcast via LDS.
// block 128 threads, grid-stride over nodes.
// ---------------------------------------------------------------------------
__global__ __launch_bounds__(128) void k_fusedM(const float* __restrict__ aggW,
                                                const int* __restrict__ x,
                                                const float* __restrict__ U1,
                                                const float* __restrict__ U2c,
                                                const float* __restrict__ Wu2,
                                                const float* __restrict__ bu2,
                                                float* __restrict__ M) {
  int c = threadIdx.x;
  float w[128];
#pragma unroll
  for (int k = 0; k < 128; k++) w[k] = Wu2[k * 128 + c];
  float b2 = bu2[c];
  __shared__ float hs[4][128];
  for (int n = blockIdx.x; n < N_NODES; n += gridDim.x) {
    int xs = x[n];
    float base = U1[xs * 128 + c] + aggW[n * 128 + c];
    __syncthreads();  // protect hs from previous iteration's readers
#pragma unroll
    for (int a = 0; a < 4; a++) {
      float h = base + U2c[a * 128 + c];
      hs[a][c] = h > 0.f ? h : 0.f;
    }
    __syncthreads();
#pragma unroll
    for (int a = 0; a < 4; a++) {
      float acc = b2;
#pragma unroll
      for (int k = 0; k < 128; k += 4) {
        float4 h4 = *(const float4*)&hs[a][k];
        acc += h4.x * w[k] + h4.y * w[k + 1] + h4.z * w[k + 2] + h4.w * w[k + 3];
      }
      M[(n * 4 + a) * 128 + c] = acc > 0.f ? acc : 0.f;
    }
  }
}

// ---------------------------------------------------------------------------
// Message scatter: agg[dst] += M[src*4 + attr]
// one wave per edge; lane handles 2 channels (float2). grid = E/4 x 256
// ---------------------------------------------------------------------------
__global__ void k_scatterM(const int* __restrict__ eidx,
                           const int* __restrict__ attr,
                           const float* __restrict__ M,
                           float* __restrict__ agg) {
  int e = blockIdx.x * 4 + (threadIdx.x >> 6);
  int lane = threadIdx.x & 63;
  int s = eidx[e];
  int d = eidx[N_EDGES + e];
  int a = attr[e];
  int c = lane * 2;
  float2 v = *(const float2*)&M[(s * 4 + a) * 128 + c];
  atomicAdd(&agg[d * 128 + c], v.x);
  atomicAdd(&agg[d * 128 + c + 1], v.y);
}

// ---------------------------------------------------------------------------
// mol_state[batch[n]] += node_state[n]
// ---------------------------------------------------------------------------
__global__ void k_mol(const float* __restrict__ node,
                      const int* __restrict__ batch,
                      float* __restrict__ mol) {
  int idx = blockIdx.x * 256 + threadIdx.x;  // over N_NODES*128
  int n = idx >> 7;
  int c = idx & 127;
  atomicAdd(&mol[batch[n] * 128 + c], node[idx]);
}

// ---------------------------------------------------------------------------
// out[m] = relu(mol[m] @ Wr1 + br1) @ Wr2 + br2
// block 256, grid NUM_MOL
// ---------------------------------------------------------------------------
__global__ __launch_bounds__(256) void k_readout(const float* __restrict__ mol,
                                                 const float* __restrict__ Wr1,
                                                 const float* __restrict__ br1,
                                                 const float* __restrict__ Wr2,
                                                 const float* __restrict__ br2,
                                                 float* __restrict__ out) {
  int m = blockIdx.x;
  __shared__ float ms[128];
  __shared__ float red[256];
  int t = threadIdx.x;
  if (t < 128) ms[t] = mol[m * 128 + t];
  __syncthreads();
  float part = 0.f;
#pragma unroll
  for (int jj = 0; jj < 2; jj++) {
    int j = t + jj * 256;
    float acc = br1[j];
#pragma unroll
    for (int k = 0; k < 128; k += 4) {
      float4 m4 = *(const float4*)&ms[k];
      acc += m4.x * Wr1[k * 512 + j] + m4.y * Wr1[(k + 1) * 512 + j] +
             m4.z * Wr1[(k + 2) * 512 + j] + m4.w * Wr1[(k + 3) * 512 + j];
    }
    acc = acc > 0.f ? acc : 0.f;
    part += acc * Wr2[j];
  }
  red[t] = part;
  __syncthreads();
  for (int s = 128; s > 0; s >>= 1) {
    if (t < s) red[t] += red[t + s];
    __syncthreads();
  }
  if (t == 0) out[m] = red[0] + br2[0];
}

// ---------------------------------------------------------------------------
extern "C" void kernel_launch(void* const* d_in, const int* in_sizes, int n_in,
                              void* d_out, int out_size, void* d_ws, size_t ws_size,
                              hipStream_t stream) {
  const int* x        = (const int*)d_in[0];
  const int* eattr    = (const int*)d_in[1];
  const int* eidx     = (const int*)d_in[2];
  const int* batch    = (const int*)d_in[3];
  const float* atom_table = (const float*)d_in[4];
  const float* bond_table = (const float*)d_in[5];
  const float* Wi  = (const float*)d_in[6];
  const float* bi  = (const float*)d_in[7];
  const float* Wu1 = (const float*)d_in[8];
  const float* bu1 = (const float*)d_in[9];
  const float* Wu2 = (const float*)d_in[10];
  const float* bu2 = (const float*)d_in[11];
  const float* Wr1 = (const float*)d_in[12];
  const float* br1 = (const float*)d_in[13];
  const float* Wr2 = (const float*)d_in[14];
  const float* br2 = (const float*)d_in[15];
  float* out = (float*)d_out;

  char* ws = (char*)d_ws;
  float* M    = (float*)(ws);                                   // 200000*128 f32 = 102,400,000 B
  float* A    = (float*)(ws + 102400000);                       // 50000*128 f32 =  25,600,000 B
  float* B    = (float*)(ws + 128000000);                       // 50000*128 f32 =  25,600,000 B
  float* T1   = (float*)(ws + 153600000);                       // 119*128 f32
  float* U1   = (float*)(ws + 153600000 + 61184);               // 119*128 f32
  float* T2c  = (float*)(ws + 153600000 + 2 * 61184);           // 4*128 f32
  float* U2c  = (float*)(ws + 153600000 + 2 * 61184 + 2048);    // 4*128 f32
  float* mol  = (float*)(ws + 153600000 + 2 * 61184 + 4096);    // 2000*128 f32

  hipMemsetAsync(A, 0, 50000 * 128 * sizeof(float), stream);
  k_tables<<<123, 128, 0, stream>>>(atom_table, bond_table, Wi, bi, Wu1, bu1,
                                    T1, U1, T2c, U2c);
  k_scatter0<<<N_EDGES / 4, 256, 0, stream>>>(x, eidx, eattr, T1, T2c, A);

  for (int p = 0; p < 4; p++) {
    k_aggW<<<2048, 128, 0, stream>>>(A, Wu1, B);
    k_fusedM<<<2048, 128, 0, stream>>>(B, x, U1, U2c, Wu2, bu2, M);
    hipMemsetAsync(A, 0, 50000 * 128 * sizeof(float), stream);
    k_scatterM<<<N_EDGES / 4, 256, 0, stream>>>(eidx, eattr, M, A);
  }

  hipMemsetAsync(mol, 0, NUM_MOL * 128 * sizeof(float), stream);
  k_mol<<<(N_NODES * 128) / 256, 256, 0, stream>>>(A, batch, mol);
  k_readout<<<NUM_MOL, 256, 0, stream>>>(mol, Wr1, br1, Wr2, br2, out);
}

// Round 2
// 2508.933 us; speedup vs baseline: 2.0336x; 2.0336x over previous
//
#include <hip/hip_runtime.h>

#define N_NODES 50000
#define N_EDGES 800000
#define NUM_MOL 2000

// ---------------------------------------------------------------------------
// Type tables:
//   T1[t,c]  = atom_table[t,:] @ Wi[0:128,c]            (119x128)
//   T2c[a,c] = bond_table[a,:] @ Wi[128:192,c] + bi[c]  (4x128)
//   U1[t,c]  = atom_table[t,:] @ Wu1[0:128,c]           (119x128)
//   U2c[a,c] = bond_table[a,:] @ Wu1[128:192,c] + bu1[c](4x128)
// grid 123 x 128
// ---------------------------------------------------------------------------
__global__ void k_tables(const float* __restrict__ atom_table,
                         const float* __restrict__ bond_table,
                         const float* __restrict__ Wi,
                         const float* __restrict__ bi,
                         const float* __restrict__ Wu1,
                         const float* __restrict__ bu1,
                         float* __restrict__ T1, float* __restrict__ U1,
                         float* __restrict__ T2c, float* __restrict__ U2c) {
  int b = blockIdx.x;
  int c = threadIdx.x;
  if (b < 119) {
    float t = 0.f, u = 0.f;
    for (int k = 0; k < 128; k++) {
      float a = atom_table[b * 128 + k];
      t += a * Wi[k * 128 + c];
      u += a * Wu1[k * 128 + c];
    }
    T1[b * 128 + c] = t;
    U1[b * 128 + c] = u;
  } else {
    int a = b - 119;
    float t = bi[c], u = bu1[c];
    for (int k = 0; k < 64; k++) {
      float bv = bond_table[a * 64 + k];
      t += bv * Wi[(128 + k) * 128 + c];
      u += bv * Wu1[(128 + k) * 128 + c];
    }
    T2c[a * 128 + c] = t;
    U2c[a * 128 + c] = u;
  }
}

// TT[x*4+a, c] = relu(T1[x,c] + T2c[a,c])  -- the 476 distinct initial messages
__global__ void k_tt(const float* __restrict__ T1, const float* __restrict__ T2c,
                     float* __restrict__ TT) {
  int r = blockIdx.x;   // 0..475
  int c = threadIdx.x;
  float v = T1[(r >> 2) * 128 + c] + T2c[(r & 3) * 128 + c];
  TT[r * 128 + c] = v > 0.f ? v : 0.f;
}

// ---------------------------------------------------------------------------
// CSR build: histogram of dst, single-block scan, fill.
// ---------------------------------------------------------------------------
__global__ void k_hist(const int* __restrict__ eidx, int* __restrict__ cnt) {
  int e = blockIdx.x * 256 + threadIdx.x;
  atomicAdd(&cnt[eidx[N_EDGES + e]], 1);
}

__global__ __launch_bounds__(1024) void k_scan(const int* __restrict__ cnt,
                                               int* __restrict__ rowptr,
                                               int* __restrict__ cursor) {
  __shared__ int buf[1024];
  __shared__ int carry_s;
  int t = threadIdx.x;
  if (t == 0) carry_s = 0;
  __syncthreads();
  for (int base = 0; base < N_NODES; base += 1024) {
    int i = base + t;
    int v = (i < N_NODES) ? cnt[i] : 0;
    buf[t] = v;
    __syncthreads();
    for (int off = 1; off < 1024; off <<= 1) {
      int add = (t >= off) ? buf[t - off] : 0;
      __syncthreads();
      buf[t] += add;
      __syncthreads();
    }
    int carry = carry_s;
    if (i < N_NODES) {
      rowptr[i + 1] = carry + buf[t];
      cursor[i] = carry + buf[t] - v;   // exclusive prefix = rowptr[i]
    }
    __syncthreads();
    if (t == 1023) carry_s = carry + buf[1023];
    __syncthreads();
  }
  if (t == 0) rowptr[0] = 0;
}

// csr[pos] = src*4 + attr, grouped by dst
__global__ void k_fill(const int* __restrict__ eidx, const int* __restrict__ attr,
                       int* __restrict__ cursor, int* __restrict__ csr) {
  int e = blockIdx.x * 256 + threadIdx.x;
  int d = eidx[N_EDGES + e];
  int pos = atomicAdd(&cursor[d], 1);
  csr[pos] = eidx[e] * 4 + attr[e];
}

// ---------------------------------------------------------------------------
// Gather initial messages: A[n] = sum_{edges into n} TT[x[src]*4+attr]
// one wave per node, 2 channels/lane. grid 12500 x 256
// ---------------------------------------------------------------------------
__global__ void k_gather0(const int* __restrict__ rowptr, const int* __restrict__ csr,
                          const int* __restrict__ x, const float* __restrict__ TT,
                          float* __restrict__ A_) {
  int n = blockIdx.x * 4 + (threadIdx.x >> 6);
  int lane = threadIdx.x & 63;
  int beg = rowptr[n], end = rowptr[n + 1];
  float ax = 0.f, ay = 0.f;
  int i = beg;
  for (; i + 1 < end; i += 2) {
    int m0 = csr[i], m1 = csr[i + 1];
    int t0 = x[m0 >> 2] * 4 + (m0 & 3);
    int t1 = x[m1 >> 2] * 4 + (m1 & 3);
    float2 v0 = *(const float2*)&TT[t0 * 128 + lane * 2];
    float2 v1 = *(const float2*)&TT[t1 * 128 + lane * 2];
    ax += v0.x + v1.x;
    ay += v0.y + v1.y;
  }
  if (i < end) {
    int m0 = csr[i];
    int t0 = x[m0 >> 2] * 4 + (m0 & 3);
    float2 v0 = *(const float2*)&TT[t0 * 128 + lane * 2];
    ax += v0.x;
    ay += v0.y;
  }
  float2 o; o.x = ax; o.y = ay;
  *(float2*)&A_[n * 128 + lane * 2] = o;
}

// ---------------------------------------------------------------------------
// Gather messages: A[n] = sum_{edges into n} M[src*4+attr]
// ---------------------------------------------------------------------------
__global__ void k_gather(const int* __restrict__ rowptr, const int* __restrict__ csr,
                         const float* __restrict__ M, float* __restrict__ A_) {
  int n = blockIdx.x * 4 + (threadIdx.x >> 6);
  int lane = threadIdx.x & 63;
  int beg = rowptr[n], end = rowptr[n + 1];
  float ax = 0.f, ay = 0.f;
  int i = beg;
  for (; i + 1 < end; i += 2) {
    int m0 = csr[i], m1 = csr[i + 1];
    float2 v0 = *(const float2*)&M[m0 * 128 + lane * 2];
    float2 v1 = *(const float2*)&M[m1 * 128 + lane * 2];
    ax += v0.x + v1.x;
    ay += v0.y + v1.y;
  }
  if (i < end) {
    int m0 = csr[i];
    float2 v0 = *(const float2*)&M[m0 * 128 + lane * 2];
    ax += v0.x;
    ay += v0.y;
  }
  float2 o; o.x = ax; o.y = ay;
  *(float2*)&A_[n * 128 + lane * 2] = o;
}

// ---------------------------------------------------------------------------
// B = A @ Wu1[192:320,:]  — one wave per node, 2 cols/lane, weights in VGPRs.
// ---------------------------------------------------------------------------
__global__ __launch_bounds__(64, 1) void k_aggW2(const float* __restrict__ A_,
                                                 const float* __restrict__ Wu1,
                                                 float* __restrict__ B_) {
  int c = threadIdx.x;  // owns cols 2c, 2c+1
  float2 w[128];
#pragma unroll
  for (int k = 0; k < 128; k++) w[k] = *(const float2*)&Wu1[(192 + k) * 128 + 2 * c];
  __shared__ float as[128];
  for (int n = blockIdx.x; n < N_NODES; n += gridDim.x) {
    __syncthreads();
    float2 av = *(const float2*)&A_[n * 128 + 2 * c];
    as[2 * c] = av.x;
    as[2 * c + 1] = av.y;
    __syncthreads();
    float acc0 = 0.f, acc1 = 0.f;
#pragma unroll
    for (int k = 0; k < 128; k += 4) {
      float4 a4 = *(const float4*)&as[k];
      acc0 += a4.x * w[k].x + a4.y * w[k + 1].x + a4.z * w[k + 2].x + a4.w * w[k + 3].x;
      acc1 += a4.x * w[k].y + a4.y * w[k + 1].y + a4.z * w[k + 2].y + a4.w * w[k + 3].y;
    }
    float2 o; o.x = acc0; o.y = acc1;
    *(float2*)&B_[n * 128 + 2 * c] = o;
  }
}

// ---------------------------------------------------------------------------
// M[n*4+a] = relu(relu(U1[x[n]] + U2c[a] + B[n]) @ Wu2 + bu2)
// one wave per node, 2 cols/lane, Wu2 columns in VGPRs, h broadcast via LDS.
// ---------------------------------------------------------------------------
__global__ __launch_bounds__(64, 1) void k_fusedM2(const float* __restrict__ B_,
                                                   const int* __restrict__ x,
                                                   const float* __restrict__ U1,
                                                   const float* __restrict__ U2c,
                                                   const float* __restrict__ Wu2,
                                                   const float* __restrict__ bu2,
                                                   float* __restrict__ M) {
  int c = threadIdx.x;  // owns cols 2c, 2c+1
  float2 w[128];
#pragma unroll
  for (int k = 0; k < 128; k++) w[k] = *(const float2*)&Wu2[k * 128 + 2 * c];
  float2 b2 = *(const float2*)&bu2[2 * c];
  __shared__ float hs[4][128];
  for (int n = blockIdx.x; n < N_NODES; n += gridDim.x) {
    int xs = x[n];
    float2 u1 = *(const float2*)&U1[xs * 128 + 2 * c];
    float2 aw = *(const float2*)&B_[n * 128 + 2 * c];
    __syncthreads();
#pragma unroll
    for (int a = 0; a < 4; a++) {
      float2 u2 = *(const float2*)&U2c[a * 128 + 2 * c];
      float h0 = u1.x + aw.x + u2.x;
      float h1 = u1.y + aw.y + u2.y;
      hs[a][2 * c] = h0 > 0.f ? h0 : 0.f;
      hs[a][2 * c + 1] = h1 > 0.f ? h1 : 0.f;
    }
    __syncthreads();
#pragma unroll
    for (int a = 0; a < 4; a++) {
      float acc0 = b2.x, acc1 = b2.y;
#pragma unroll
      for (int k = 0; k < 128; k += 4) {
        float4 h4 = *(const float4*)&hs[a][k];
        acc0 += h4.x * w[k].x + h4.y * w[k + 1].x + h4.z * w[k + 2].x + h4.w * w[k + 3].x;
        acc1 += h4.x * w[k].y + h4.y * w[k + 1].y + h4.z * w[k + 2].y + h4.w * w[k + 3].y;
      }
      float2 o;
      o.x = acc0 > 0.f ? acc0 : 0.f;
      o.y = acc1 > 0.f ? acc1 : 0.f;
      *(float2*)&M[(n * 4 + a) * 128 + 2 * c] = o;
    }
  }
}

// ---------------------------------------------------------------------------
// mol_state[batch[n]] += node_state[n]   (small: 6.4M atomics)
// ---------------------------------------------------------------------------
__global__ void k_mol(const float* __restrict__ node,
                      const int* __restrict__ batch,
                      float* __restrict__ mol) {
  int idx = blockIdx.x * 256 + threadIdx.x;  // over N_NODES*128
  int n = idx >> 7;
  int c = idx & 127;
  atomicAdd(&mol[batch[n] * 128 + c], node[idx]);
}

// ---------------------------------------------------------------------------
// out[m] = relu(mol[m] @ Wr1 + br1) @ Wr2 + br2
// ---------------------------------------------------------------------------
__global__ __launch_bounds__(256) void k_readout(const float* __restrict__ mol,
                                                 const float* __restrict__ Wr1,
                                                 const float* __restrict__ br1,
                                                 const float* __restrict__ Wr2,
                                                 const float* __restrict__ br2,
                                                 float* __restrict__ out) {
  int m = blockIdx.x;
  __shared__ float ms[128];
  __shared__ float red[256];
  int t = threadIdx.x;
  if (t < 128) ms[t] = mol[m * 128 + t];
  __syncthreads();
  float part = 0.f;
#pragma unroll
  for (int jj = 0; jj < 2; jj++) {
    int j = t + jj * 256;
    float acc = br1[j];
#pragma unroll
    for (int k = 0; k < 128; k += 4) {
      float4 m4 = *(const float4*)&ms[k];
      acc += m4.x * Wr1[k * 512 + j] + m4.y * Wr1[(k + 1) * 512 + j] +
             m4.z * Wr1[(k + 2) * 512 + j] + m4.w * Wr1[(k + 3) * 512 + j];
    }
    acc = acc > 0.f ? acc : 0.f;
    part += acc * Wr2[j];
  }
  red[t] = part;
  __syncthreads();
  for (int s = 128; s > 0; s >>= 1) {
    if (t < s) red[t] += red[t + s];
    __syncthreads();
  }
  if (t == 0) out[m] = red[0] + br2[0];
}

// ---------------------------------------------------------------------------
extern "C" void kernel_launch(void* const* d_in, const int* in_sizes, int n_in,
                              void* d_out, int out_size, void* d_ws, size_t ws_size,
                              hipStream_t stream) {
  const int* x        = (const int*)d_in[0];
  const int* eattr    = (const int*)d_in[1];
  const int* eidx     = (const int*)d_in[2];
  const int* batch    = (const int*)d_in[3];
  const float* atom_table = (const float*)d_in[4];
  const float* bond_table = (const float*)d_in[5];
  const float* Wi  = (const float*)d_in[6];
  const float* bi  = (const float*)d_in[7];
  const float* Wu1 = (const float*)d_in[8];
  const float* bu1 = (const float*)d_in[9];
  const float* Wu2 = (const float*)d_in[10];
  const float* bu2 = (const float*)d_in[11];
  const float* Wr1 = (const float*)d_in[12];
  const float* br1 = (const float*)d_in[13];
  const float* Wr2 = (const float*)d_in[14];
  const float* br2 = (const float*)d_in[15];
  float* out = (float*)d_out;

  char* ws = (char*)d_ws;
  float* M      = (float*)(ws);                    // 102,400,000 B
  float* A      = (float*)(ws + 102400000);        //  25,600,000 B
  float* B      = (float*)(ws + 128000000);        //  25,600,000 B
  int*   csr    = (int*)  (ws + 153600000);        //   3,200,000 B
  int*   rowptr = (int*)  (ws + 156800000);        //     200,064 B (50001 ints)
  float* T1     = (float*)(ws + 157000064);        //      60,928 B
  float* U1     = (float*)(ws + 157061000 - 8);    //      60,928 B  (157,060,992)
  float* T2c    = (float*)(ws + 157121920);        //       2,048 B
  float* U2c    = (float*)(ws + 157123968);        //       2,048 B
  float* TT     = (float*)(ws + 157126016);        //     243,712 B
  float* mol    = (float*)(ws + 157369728);        //   1,024,000 B
  // cnt/cursor alias B: only live before the first k_aggW2 write to B.
  int*   cnt    = (int*)B;                         //     200,000 B
  int*   cursor = (int*)(ws + 128000000 + 204800); //     200,000 B

  hipMemsetAsync(cnt, 0, N_NODES * sizeof(int), stream);
  k_tables<<<123, 128, 0, stream>>>(atom_table, bond_table, Wi, bi, Wu1, bu1,
                                    T1, U1, T2c, U2c);
  k_tt<<<476, 128, 0, stream>>>(T1, T2c, TT);
  k_hist<<<N_EDGES / 256, 256, 0, stream>>>(eidx, cnt);
  k_scan<<<1, 1024, 0, stream>>>(cnt, rowptr, cursor);
  k_fill<<<N_EDGES / 256, 256, 0, stream>>>(eidx, eattr, cursor, csr);

  k_gather0<<<N_NODES / 4, 256, 0, stream>>>(rowptr, csr, x, TT, A);

  for (int p = 0; p < 4; p++) {
    k_aggW2<<<2048, 64, 0, stream>>>(A, Wu1, B);
    k_fusedM2<<<2048, 64, 0, stream>>>(B, x, U1, U2c, Wu2, bu2, M);
    k_gather<<<N_NODES / 4, 256, 0, stream>>>(rowptr, csr, M, A);
  }

  hipMemsetAsync(mol, 0, NUM_MOL * 128 * sizeof(float), stream);
  k_mol<<<(N_NODES * 128) / 256, 256, 0, stream>>>(A, batch, mol);
  k_readout<<<NUM_MOL, 256, 0, stream>>>(mol, Wr1, br1, Wr2, br2, out);
}

// Round 3
// 1243.370 us; speedup vs baseline: 4.1034x; 2.0178x over previous
//
#include <hip/hip_runtime.h>

#define N_NODES 50000
#define N_EDGES 800000
#define NUM_MOL 2000

// ---------------------------------------------------------------------------
// Type tables:
//   T1[t,c]  = atom_table[t,:] @ Wi[0:128,c]            (119x128)
//   T2c[a,c] = bond_table[a,:] @ Wi[128:192,c] + bi[c]  (4x128)
//   U1[t,c]  = atom_table[t,:] @ Wu1[0:128,c]           (119x128)
//   U2c[a,c] = bond_table[a,:] @ Wu1[128:192,c] + bu1[c](4x128)
// ---------------------------------------------------------------------------
__global__ void k_tables(const float* __restrict__ atom_table,
                         const float* __restrict__ bond_table,
                         const float* __restrict__ Wi,
                         const float* __restrict__ bi,
                         const float* __restrict__ Wu1,
                         const float* __restrict__ bu1,
                         float* __restrict__ T1, float* __restrict__ U1,
                         float* __restrict__ T2c, float* __restrict__ U2c) {
  int b = blockIdx.x;
  int c = threadIdx.x;
  if (b < 119) {
    float t = 0.f, u = 0.f;
    for (int k = 0; k < 128; k++) {
      float a = atom_table[b * 128 + k];
      t += a * Wi[k * 128 + c];
      u += a * Wu1[k * 128 + c];
    }
    T1[b * 128 + c] = t;
    U1[b * 128 + c] = u;
  } else {
    int a = b - 119;
    float t = bi[c], u = bu1[c];
    for (int k = 0; k < 64; k++) {
      float bv = bond_table[a * 64 + k];
      t += bv * Wi[(128 + k) * 128 + c];
      u += bv * Wu1[(128 + k) * 128 + c];
    }
    T2c[a * 128 + c] = t;
    U2c[a * 128 + c] = u;
  }
}

// TT[x*4+a, c] = relu(T1[x,c] + T2c[a,c])
__global__ void k_tt(const float* __restrict__ T1, const float* __restrict__ T2c,
                     float* __restrict__ TT) {
  int r = blockIdx.x;   // 0..475
  int c = threadIdx.x;
  float v = T1[(r >> 2) * 128 + c] + T2c[(r & 3) * 128 + c];
  TT[r * 128 + c] = v > 0.f ? v : 0.f;
}

// ---------------------------------------------------------------------------
// CSR build: histogram of dst, single-block scan, fill.
// ---------------------------------------------------------------------------
__global__ void k_hist(const int* __restrict__ eidx, int* __restrict__ cnt) {
  int e = blockIdx.x * 256 + threadIdx.x;
  atomicAdd(&cnt[eidx[N_EDGES + e]], 1);
}

__global__ __launch_bounds__(1024) void k_scan(const int* __restrict__ cnt,
                                               int* __restrict__ rowptr,
                                               int* __restrict__ cursor) {
  __shared__ int buf[1024];
  __shared__ int carry_s;
  int t = threadIdx.x;
  if (t == 0) carry_s = 0;
  __syncthreads();
  for (int base = 0; base < N_NODES; base += 1024) {
    int i = base + t;
    int v = (i < N_NODES) ? cnt[i] : 0;
    buf[t] = v;
    __syncthreads();
    for (int off = 1; off < 1024; off <<= 1) {
      int add = (t >= off) ? buf[t - off] : 0;
      __syncthreads();
      buf[t] += add;
      __syncthreads();
    }
    int carry = carry_s;
    if (i < N_NODES) {
      rowptr[i + 1] = carry + buf[t];
      cursor[i] = carry + buf[t] - v;   // exclusive prefix
    }
    __syncthreads();
    if (t == 1023) carry_s = carry + buf[1023];
    __syncthreads();
  }
  if (t == 0) rowptr[0] = 0;
}

__global__ void k_fill(const int* __restrict__ eidx, const int* __restrict__ attr,
                       int* __restrict__ cursor, int* __restrict__ csr) {
  int e = blockIdx.x * 256 + threadIdx.x;
  int d = eidx[N_EDGES + e];
  int pos = atomicAdd(&cursor[d], 1);
  csr[pos] = eidx[e] * 4 + attr[e];
}

// ---------------------------------------------------------------------------
// Gather initial messages: A[n] = sum_{edges into n} TT[x[src]*4+attr]
// ---------------------------------------------------------------------------
__global__ void k_gather0(const int* __restrict__ rowptr, const int* __restrict__ csr,
                          const int* __restrict__ x, const float* __restrict__ TT,
                          float* __restrict__ A_) {
  int n = blockIdx.x * 4 + (threadIdx.x >> 6);
  int lane = threadIdx.x & 63;
  int beg = rowptr[n], end = rowptr[n + 1];
  float ax = 0.f, ay = 0.f;
  int i = beg;
  for (; i + 1 < end; i += 2) {
    int m0 = csr[i], m1 = csr[i + 1];
    int t0 = x[m0 >> 2] * 4 + (m0 & 3);
    int t1 = x[m1 >> 2] * 4 + (m1 & 3);
    float2 v0 = *(const float2*)&TT[t0 * 128 + lane * 2];
    float2 v1 = *(const float2*)&TT[t1 * 128 + lane * 2];
    ax += v0.x + v1.x;
    ay += v0.y + v1.y;
  }
  if (i < end) {
    int m0 = csr[i];
    int t0 = x[m0 >> 2] * 4 + (m0 & 3);
    float2 v0 = *(const float2*)&TT[t0 * 128 + lane * 2];
    ax += v0.x;
    ay += v0.y;
  }
  float2 o; o.x = ax; o.y = ay;
  *(float2*)&A_[n * 128 + lane * 2] = o;
}

// ---------------------------------------------------------------------------
// Gather messages: A[n] = sum_{edges into n} M[src*4+attr]
// ---------------------------------------------------------------------------
__global__ void k_gather(const int* __restrict__ rowptr, const int* __restrict__ csr,
                         const float* __restrict__ M, float* __restrict__ A_) {
  int n = blockIdx.x * 4 + (threadIdx.x >> 6);
  int lane = threadIdx.x & 63;
  int beg = rowptr[n], end = rowptr[n + 1];
  float ax = 0.f, ay = 0.f;
  int i = beg;
  for (; i + 1 < end; i += 2) {
    int m0 = csr[i], m1 = csr[i + 1];
    float2 v0 = *(const float2*)&M[m0 * 128 + lane * 2];
    float2 v1 = *(const float2*)&M[m1 * 128 + lane * 2];
    ax += v0.x + v1.x;
    ay += v0.y + v1.y;
  }
  if (i < end) {
    int m0 = csr[i];
    float2 v0 = *(const float2*)&M[m0 * 128 + lane * 2];
    ax += v0.x;
    ay += v0.y;
  }
  float2 o; o.x = ax; o.y = ay;
  *(float2*)&A_[n * 128 + lane * 2] = o;
}

// ---------------------------------------------------------------------------
// k_mm1: B = A @ Wu1[192:320,:]   tiled GEMM, 64-row tile, 4x8 micro-tile.
// LDS stride 132 -> h broadcast reads are 2-way bank aliased (free, m136).
// ---------------------------------------------------------------------------
__global__ __launch_bounds__(256) void k_mm1(const float* __restrict__ A_,
                                             const float* __restrict__ Wu1,
                                             float* __restrict__ B_) {
  __shared__ float Hs[64][132];
  int t = threadIdx.x;
  int base = blockIdx.x * 64;
#pragma unroll
  for (int j = 0; j < 8; j++) {
    int idx = j * 256 + t;        // 0..2047 float4 slots
    int rr = idx >> 5;            // local row
    int kq = idx & 31;            // float4 index in k
    int n = base + rr;
    if (n >= N_NODES) n = N_NODES - 1;
    float4 v = *(const float4*)&A_[n * 128 + kq * 4];
    *(float4*)&Hs[rr][kq * 4] = v;
  }
  __syncthreads();
  int r0 = (t >> 4) * 4;
  int c0 = (t & 15) * 8;
  const float* W = Wu1 + 192 * 128;
  float acc[4][8];
#pragma unroll
  for (int i = 0; i < 4; i++)
#pragma unroll
    for (int j = 0; j < 8; j++) acc[i][j] = 0.f;
#pragma unroll 4
  for (int k = 0; k < 128; k++) {
    float4 w0 = *(const float4*)&W[k * 128 + c0];
    float4 w1 = *(const float4*)&W[k * 128 + c0 + 4];
    float h0 = Hs[r0][k], h1 = Hs[r0 + 1][k], h2 = Hs[r0 + 2][k], h3 = Hs[r0 + 3][k];
    acc[0][0] += h0 * w0.x; acc[0][1] += h0 * w0.y; acc[0][2] += h0 * w0.z; acc[0][3] += h0 * w0.w;
    acc[0][4] += h0 * w1.x; acc[0][5] += h0 * w1.y; acc[0][6] += h0 * w1.z; acc[0][7] += h0 * w1.w;
    acc[1][0] += h1 * w0.x; acc[1][1] += h1 * w0.y; acc[1][2] += h1 * w0.z; acc[1][3] += h1 * w0.w;
    acc[1][4] += h1 * w1.x; acc[1][5] += h1 * w1.y; acc[1][6] += h1 * w1.z; acc[1][7] += h1 * w1.w;
    acc[2][0] += h2 * w0.x; acc[2][1] += h2 * w0.y; acc[2][2] += h2 * w0.z; acc[2][3] += h2 * w0.w;
    acc[2][4] += h2 * w1.x; acc[2][5] += h2 * w1.y; acc[2][6] += h2 * w1.z; acc[2][7] += h2 * w1.w;
    acc[3][0] += h3 * w0.x; acc[3][1] += h3 * w0.y; acc[3][2] += h3 * w0.z; acc[3][3] += h3 * w0.w;
    acc[3][4] += h3 * w1.x; acc[3][5] += h3 * w1.y; acc[3][6] += h3 * w1.z; acc[3][7] += h3 * w1.w;
  }
#pragma unroll
  for (int i = 0; i < 4; i++) {
    int n = base + r0 + i;
    if (n < N_NODES) {
      float4 o0, o1;
      o0.x = acc[i][0]; o0.y = acc[i][1]; o0.z = acc[i][2]; o0.w = acc[i][3];
      o1.x = acc[i][4]; o1.y = acc[i][5]; o1.z = acc[i][6]; o1.w = acc[i][7];
      *(float4*)&B_[n * 128 + c0] = o0;
      *(float4*)&B_[n * 128 + c0 + 4] = o1;
    }
  }
}

// ---------------------------------------------------------------------------
// k_mm2: M[n*4+a] = relu( relu(U1[x[n]] + U2c[a] + B[n]) @ Wu2 + bu2 )
// Same tiling; H tile (16 nodes x 4 attrs = 64 rows) formed during staging.
// ---------------------------------------------------------------------------
__global__ __launch_bounds__(256) void k_mm2(const float* __restrict__ B_,
                                             const int* __restrict__ x,
                                             const float* __restrict__ U1,
                                             const float* __restrict__ U2c,
                                             const float* __restrict__ Wu2,
                                             const float* __restrict__ bu2,
                                             float* __restrict__ M) {
  __shared__ float Hs[64][132];
  __shared__ int xs[16];
  int t = threadIdx.x;
  int nbase = blockIdx.x * 16;
  if (t < 16) xs[t] = x[nbase + t];
  __syncthreads();
#pragma unroll
  for (int j = 0; j < 8; j++) {
    int idx = j * 256 + t;
    int rr = idx >> 5;            // local row = nl*4 + a
    int kq = idx & 31;
    int nl = rr >> 2, a = rr & 3;
    float4 u1 = *(const float4*)&U1[xs[nl] * 128 + kq * 4];
    float4 bb = *(const float4*)&B_[(nbase + nl) * 128 + kq * 4];
    float4 u2 = *(const float4*)&U2c[a * 128 + kq * 4];
    float4 h;
    h.x = u1.x + bb.x + u2.x; h.y = u1.y + bb.y + u2.y;
    h.z = u1.z + bb.z + u2.z; h.w = u1.w + bb.w + u2.w;
    h.x = h.x > 0.f ? h.x : 0.f; h.y = h.y > 0.f ? h.y : 0.f;
    h.z = h.z > 0.f ? h.z : 0.f; h.w = h.w > 0.f ? h.w : 0.f;
    *(float4*)&Hs[rr][kq * 4] = h;
  }
  __syncthreads();
  int r0 = (t >> 4) * 4;
  int c0 = (t & 15) * 8;
  float4 bias0 = *(const float4*)&bu2[c0];
  float4 bias1 = *(const float4*)&bu2[c0 + 4];
  float acc[4][8];
#pragma unroll
  for (int i = 0; i < 4; i++) {
    acc[i][0] = bias0.x; acc[i][1] = bias0.y; acc[i][2] = bias0.z; acc[i][3] = bias0.w;
    acc[i][4] = bias1.x; acc[i][5] = bias1.y; acc[i][6] = bias1.z; acc[i][7] = bias1.w;
  }
#pragma unroll 4
  for (int k = 0; k < 128; k++) {
    float4 w0 = *(const float4*)&Wu2[k * 128 + c0];
    float4 w1 = *(const float4*)&Wu2[k * 128 + c0 + 4];
    float h0 = Hs[r0][k], h1 = Hs[r0 + 1][k], h2 = Hs[r0 + 2][k], h3 = Hs[r0 + 3][k];
    acc[0][0] += h0 * w0.x; acc[0][1] += h0 * w0.y; acc[0][2] += h0 * w0.z; acc[0][3] += h0 * w0.w;
    acc[0][4] += h0 * w1.x; acc[0][5] += h0 * w1.y; acc[0][6] += h0 * w1.z; acc[0][7] += h0 * w1.w;
    acc[1][0] += h1 * w0.x; acc[1][1] += h1 * w0.y; acc[1][2] += h1 * w0.z; acc[1][3] += h1 * w0.w;
    acc[1][4] += h1 * w1.x; acc[1][5] += h1 * w1.y; acc[1][6] += h1 * w1.z; acc[1][7] += h1 * w1.w;
    acc[2][0] += h2 * w0.x; acc[2][1] += h2 * w0.y; acc[2][2] += h2 * w0.z; acc[2][3] += h2 * w0.w;
    acc[2][4] += h2 * w1.x; acc[2][5] += h2 * w1.y; acc[2][6] += h2 * w1.z; acc[2][7] += h2 * w1.w;
    acc[3][0] += h3 * w0.x; acc[3][1] += h3 * w0.y; acc[3][2] += h3 * w0.z; acc[3][3] += h3 * w0.w;
    acc[3][4] += h3 * w1.x; acc[3][5] += h3 * w1.y; acc[3][6] += h3 * w1.z; acc[3][7] += h3 * w1.w;
  }
  int rowbase = nbase * 4;
#pragma unroll
  for (int i = 0; i < 4; i++) {
    float4 o0, o1;
    o0.x = acc[i][0] > 0.f ? acc[i][0] : 0.f;
    o0.y = acc[i][1] > 0.f ? acc[i][1] : 0.f;
    o0.z = acc[i][2] > 0.f ? acc[i][2] : 0.f;
    o0.w = acc[i][3] > 0.f ? acc[i][3] : 0.f;
    o1.x = acc[i][4] > 0.f ? acc[i][4] : 0.f;
    o1.y = acc[i][5] > 0.f ? acc[i][5] : 0.f;
    o1.z = acc[i][6] > 0.f ? acc[i][6] : 0.f;
    o1.w = acc[i][7] > 0.f ? acc[i][7] : 0.f;
    *(float4*)&M[(rowbase + r0 + i) * 128 + c0] = o0;
    *(float4*)&M[(rowbase + r0 + i) * 128 + c0 + 4] = o1;
  }
}

// ---------------------------------------------------------------------------
// mol_state[batch[n]] += node_state[n]
// ---------------------------------------------------------------------------
__global__ void k_mol(const float* __restrict__ node,
                      const int* __restrict__ batch,
                      float* __restrict__ mol) {
  int idx = blockIdx.x * 256 + threadIdx.x;
  int n = idx >> 7;
  int c = idx & 127;
  atomicAdd(&mol[batch[n] * 128 + c], node[idx]);
}

// ---------------------------------------------------------------------------
// out[m] = relu(mol[m] @ Wr1 + br1) @ Wr2 + br2
// ---------------------------------------------------------------------------
__global__ __launch_bounds__(256) void k_readout(const float* __restrict__ mol,
                                                 const float* __restrict__ Wr1,
                                                 const float* __restrict__ br1,
                                                 const float* __restrict__ Wr2,
                                                 const float* __restrict__ br2,
                                                 float* __restrict__ out) {
  int m = blockIdx.x;
  __shared__ float ms[128];
  __shared__ float red[256];
  int t = threadIdx.x;
  if (t < 128) ms[t] = mol[m * 128 + t];
  __syncthreads();
  float part = 0.f;
#pragma unroll
  for (int jj = 0; jj < 2; jj++) {
    int j = t + jj * 256;
    float acc = br1[j];
#pragma unroll
    for (int k = 0; k < 128; k += 4) {
      float4 m4 = *(const float4*)&ms[k];
      acc += m4.x * Wr1[k * 512 + j] + m4.y * Wr1[(k + 1) * 512 + j] +
             m4.z * Wr1[(k + 2) * 512 + j] + m4.w * Wr1[(k + 3) * 512 + j];
    }
    acc = acc > 0.f ? acc : 0.f;
    part += acc * Wr2[j];
  }
  red[t] = part;
  __syncthreads();
  for (int s = 128; s > 0; s >>= 1) {
    if (t < s) red[t] += red[t + s];
    __syncthreads();
  }
  if (t == 0) out[m] = red[0] + br2[0];
}

// ---------------------------------------------------------------------------
extern "C" void kernel_launch(void* const* d_in, const int* in_sizes, int n_in,
                              void* d_out, int out_size, void* d_ws, size_t ws_size,
                              hipStream_t stream) {
  const int* x        = (const int*)d_in[0];
  const int* eattr    = (const int*)d_in[1];
  const int* eidx     = (const int*)d_in[2];
  const int* batch    = (const int*)d_in[3];
  const float* atom_table = (const float*)d_in[4];
  const float* bond_table = (const float*)d_in[5];
  const float* Wi  = (const float*)d_in[6];
  const float* bi  = (const float*)d_in[7];
  const float* Wu1 = (const float*)d_in[8];
  const float* bu1 = (const float*)d_in[9];
  const float* Wu2 = (const float*)d_in[10];
  const float* bu2 = (const float*)d_in[11];
  const float* Wr1 = (const float*)d_in[12];
  const float* br1 = (const float*)d_in[13];
  const float* Wr2 = (const float*)d_in[14];
  const float* br2 = (const float*)d_in[15];
  float* out = (float*)d_out;

  char* ws = (char*)d_ws;
  float* M      = (float*)(ws);                    // 102,400,000 B
  float* A      = (float*)(ws + 102400000);        //  25,600,000 B
  float* B      = (float*)(ws + 128000000);        //  25,600,000 B
  int*   csr    = (int*)  (ws + 153600000);        //   3,200,000 B
  int*   rowptr = (int*)  (ws + 156800000);        //     200,064 B
  float* T1     = (float*)(ws + 157000064);        //      60,928 B
  float* U1     = (float*)(ws + 157060992);        //      60,928 B
  float* T2c    = (float*)(ws + 157121920);        //       2,048 B
  float* U2c    = (float*)(ws + 157123968);        //       2,048 B
  float* TT     = (float*)(ws + 157126016);        //     243,712 B
  float* mol    = (float*)(ws + 157369728);        //   1,024,000 B
  // cnt/cursor alias B: only live before the first k_mm1 write to B.
  int*   cnt    = (int*)B;
  int*   cursor = (int*)(ws + 128000000 + 204800);

  hipMemsetAsync(cnt, 0, N_NODES * sizeof(int), stream);
  k_tables<<<123, 128, 0, stream>>>(atom_table, bond_table, Wi, bi, Wu1, bu1,
                                    T1, U1, T2c, U2c);
  k_tt<<<476, 128, 0, stream>>>(T1, T2c, TT);
  k_hist<<<N_EDGES / 256, 256, 0, stream>>>(eidx, cnt);
  k_scan<<<1, 1024, 0, stream>>>(cnt, rowptr, cursor);
  k_fill<<<N_EDGES / 256, 256, 0, stream>>>(eidx, eattr, cursor, csr);

  k_gather0<<<N_NODES / 4, 256, 0, stream>>>(rowptr, csr, x, TT, A);

  for (int p = 0; p < 4; p++) {
    k_mm1<<<(N_NODES + 63) / 64, 256, 0, stream>>>(A, Wu1, B);
    k_mm2<<<(4 * N_NODES) / 64, 256, 0, stream>>>(B, x, U1, U2c, Wu2, bu2, M);
    k_gather<<<N_NODES / 4, 256, 0, stream>>>(rowptr, csr, M, A);
  }

  hipMemsetAsync(mol, 0, NUM_MOL * 128 * sizeof(float), stream);
  k_mol<<<(N_NODES * 128) / 256, 256, 0, stream>>>(A, batch, mol);
  k_readout<<<NUM_MOL, 256, 0, stream>>>(mol, Wr1, br1, Wr2, br2, out);
}

// Round 4
// 1189.235 us; speedup vs baseline: 4.2902x; 1.0455x over previous
//
#include <hip/hip_runtime.h>
#include <hip/hip_bf16.h>

#define N_NODES 50000
#define N_EDGES 800000
#define NUM_MOL 2000

// ---------------------------------------------------------------------------
// Type tables:
//   T1[t,c]  = atom_table[t,:] @ Wi[0:128,c]            (119x128)
//   T2c[a,c] = bond_table[a,:] @ Wi[128:192,c] + bi[c]  (4x128)
//   U1[t,c]  = atom_table[t,:] @ Wu1[0:128,c]           (119x128)
//   U2c[a,c] = bond_table[a,:] @ Wu1[128:192,c] + bu1[c](4x128)
// ---------------------------------------------------------------------------
__global__ void k_tables(const float* __restrict__ atom_table,
                         const float* __restrict__ bond_table,
                         const float* __restrict__ Wi,
                         const float* __restrict__ bi,
                         const float* __restrict__ Wu1,
                         const float* __restrict__ bu1,
                         float* __restrict__ T1, float* __restrict__ U1,
                         float* __restrict__ T2c, float* __restrict__ U2c) {
  int b = blockIdx.x;
  int c = threadIdx.x;
  if (b < 119) {
    float t = 0.f, u = 0.f;
    for (int k = 0; k < 128; k++) {
      float a = atom_table[b * 128 + k];
      t += a * Wi[k * 128 + c];
      u += a * Wu1[k * 128 + c];
    }
    T1[b * 128 + c] = t;
    U1[b * 128 + c] = u;
  } else {
    int a = b - 119;
    float t = bi[c], u = bu1[c];
    for (int k = 0; k < 64; k++) {
      float bv = bond_table[a * 64 + k];
      t += bv * Wi[(128 + k) * 128 + c];
      u += bv * Wu1[(128 + k) * 128 + c];
    }
    T2c[a * 128 + c] = t;
    U2c[a * 128 + c] = u;
  }
}

// TT[x*4+a, c] = relu(T1[x,c] + T2c[a,c])
__global__ void k_tt(const float* __restrict__ T1, const float* __restrict__ T2c,
                     float* __restrict__ TT) {
  int r = blockIdx.x;   // 0..475
  int c = threadIdx.x;
  float v = T1[(r >> 2) * 128 + c] + T2c[(r & 3) * 128 + c];
  TT[r * 128 + c] = v > 0.f ? v : 0.f;
}

// ---------------------------------------------------------------------------
// CSR build: histogram of dst, single-block scan, fill.
// ---------------------------------------------------------------------------
__global__ void k_hist(const int* __restrict__ eidx, int* __restrict__ cnt) {
  int e = blockIdx.x * 256 + threadIdx.x;
  atomicAdd(&cnt[eidx[N_EDGES + e]], 1);
}

__global__ __launch_bounds__(1024) void k_scan(const int* __restrict__ cnt,
                                               int* __restrict__ rowptr,
                                               int* __restrict__ cursor) {
  __shared__ int buf[1024];
  __shared__ int carry_s;
  int t = threadIdx.x;
  if (t == 0) carry_s = 0;
  __syncthreads();
  for (int base = 0; base < N_NODES; base += 1024) {
    int i = base + t;
    int v = (i < N_NODES) ? cnt[i] : 0;
    buf[t] = v;
    __syncthreads();
    for (int off = 1; off < 1024; off <<= 1) {
      int add = (t >= off) ? buf[t - off] : 0;
      __syncthreads();
      buf[t] += add;
      __syncthreads();
    }
    int carry = carry_s;
    if (i < N_NODES) {
      rowptr[i + 1] = carry + buf[t];
      cursor[i] = carry + buf[t] - v;   // exclusive prefix
    }
    __syncthreads();
    if (t == 1023) carry_s = carry + buf[1023];
    __syncthreads();
  }
  if (t == 0) rowptr[0] = 0;
}

__global__ void k_fill(const int* __restrict__ eidx, const int* __restrict__ attr,
                       int* __restrict__ cursor, int* __restrict__ csr) {
  int e = blockIdx.x * 256 + threadIdx.x;
  int d = eidx[N_EDGES + e];
  int pos = atomicAdd(&cursor[d], 1);
  csr[pos] = eidx[e] * 4 + attr[e];
}

// ---------------------------------------------------------------------------
// Gather initial messages: A[n] = sum_{edges into n} TT[x[src]*4+attr]  (fp32)
// ---------------------------------------------------------------------------
__global__ void k_gather0(const int* __restrict__ rowptr, const int* __restrict__ csr,
                          const int* __restrict__ x, const float* __restrict__ TT,
                          float* __restrict__ A_) {
  int n = blockIdx.x * 4 + (threadIdx.x >> 6);
  int lane = threadIdx.x & 63;
  int beg = rowptr[n], end = rowptr[n + 1];
  float ax = 0.f, ay = 0.f;
  int i = beg;
  for (; i + 1 < end; i += 2) {
    int m0 = csr[i], m1 = csr[i + 1];
    int t0 = x[m0 >> 2] * 4 + (m0 & 3);
    int t1 = x[m1 >> 2] * 4 + (m1 & 3);
    float2 v0 = *(const float2*)&TT[t0 * 128 + lane * 2];
    float2 v1 = *(const float2*)&TT[t1 * 128 + lane * 2];
    ax += v0.x + v1.x;
    ay += v0.y + v1.y;
  }
  if (i < end) {
    int m0 = csr[i];
    int t0 = x[m0 >> 2] * 4 + (m0 & 3);
    float2 v0 = *(const float2*)&TT[t0 * 128 + lane * 2];
    ax += v0.x;
    ay += v0.y;
  }
  float2 o; o.x = ax; o.y = ay;
  *(float2*)&A_[n * 128 + lane * 2] = o;
}

// ---------------------------------------------------------------------------
// Gather messages: A[n] = sum_{edges into n} M_bf16[src*4+attr]
// lane reads 2 bf16 (one dword) -> full 256 B row in one wave instruction.
// ---------------------------------------------------------------------------
__global__ void k_gather(const int* __restrict__ rowptr, const int* __restrict__ csr,
                         const __hip_bfloat16* __restrict__ M, float* __restrict__ A_) {
  int n = blockIdx.x * 4 + (threadIdx.x >> 6);
  int lane = threadIdx.x & 63;
  int beg = rowptr[n], end = rowptr[n + 1];
  float ax = 0.f, ay = 0.f;
  int i = beg;
  for (; i + 1 < end; i += 2) {
    int m0 = csr[i], m1 = csr[i + 1];
    float2 v0 = __bfloat1622float2(*(const __hip_bfloat162*)&M[m0 * 128 + lane * 2]);
    float2 v1 = __bfloat1622float2(*(const __hip_bfloat162*)&M[m1 * 128 + lane * 2]);
    ax += v0.x + v1.x;
    ay += v0.y + v1.y;
  }
  if (i < end) {
    int m0 = csr[i];
    float2 v0 = __bfloat1622float2(*(const __hip_bfloat162*)&M[m0 * 128 + lane * 2]);
    ax += v0.x;
    ay += v0.y;
  }
  float2 o; o.x = ax; o.y = ay;
  *(float2*)&A_[n * 128 + lane * 2] = o;
}

// ---------------------------------------------------------------------------
// k_mm1: B = A @ Wu1[192:320,:]   64-row tile, 4x8 micro-tile, k-quad inner
// loop with ds_read_b128 h reads.
// ---------------------------------------------------------------------------
__global__ __launch_bounds__(256, 4) void k_mm1(const float* __restrict__ A_,
                                                const float* __restrict__ Wu1,
                                                float* __restrict__ B_) {
  __shared__ float Hs[64][132];
  int t = threadIdx.x;
  int base = blockIdx.x * 64;
#pragma unroll
  for (int j = 0; j < 8; j++) {
    int idx = j * 256 + t;        // 0..2047 float4 slots
    int rr = idx >> 5;            // local row
    int kq = idx & 31;            // float4 index in k
    int n = base + rr;
    if (n >= N_NODES) n = N_NODES - 1;
    float4 v = *(const float4*)&A_[n * 128 + kq * 4];
    *(float4*)&Hs[rr][kq * 4] = v;
  }
  __syncthreads();
  int r0 = (t >> 4) * 4;
  int c0 = (t & 15) * 8;
  const float* W = Wu1 + 192 * 128;
  float acc[4][8];
#pragma unroll
  for (int r = 0; r < 4; r++)
#pragma unroll
    for (int j = 0; j < 8; j++) acc[r][j] = 0.f;
#pragma unroll 2
  for (int kq = 0; kq < 32; kq++) {
    const int k = kq * 4;
    float h0[4], h1[4], h2[4], h3[4];
    *(float4*)h0 = *(const float4*)&Hs[r0][k];
    *(float4*)h1 = *(const float4*)&Hs[r0 + 1][k];
    *(float4*)h2 = *(const float4*)&Hs[r0 + 2][k];
    *(float4*)h3 = *(const float4*)&Hs[r0 + 3][k];
#pragma unroll
    for (int i = 0; i < 4; i++) {
      float w[8];
      *(float4*)&w[0] = *(const float4*)&W[(k + i) * 128 + c0];
      *(float4*)&w[4] = *(const float4*)&W[(k + i) * 128 + c0 + 4];
      float hv[4] = {h0[i], h1[i], h2[i], h3[i]};
#pragma unroll
      for (int r = 0; r < 4; r++)
#pragma unroll
        for (int j = 0; j < 8; j++) acc[r][j] += hv[r] * w[j];
    }
  }
#pragma unroll
  for (int r = 0; r < 4; r++) {
    int n = base + r0 + r;
    if (n < N_NODES) {
      float4 o0, o1;
      o0.x = acc[r][0]; o0.y = acc[r][1]; o0.z = acc[r][2]; o0.w = acc[r][3];
      o1.x = acc[r][4]; o1.y = acc[r][5]; o1.z = acc[r][6]; o1.w = acc[r][7];
      *(float4*)&B_[n * 128 + c0] = o0;
      *(float4*)&B_[n * 128 + c0 + 4] = o1;
    }
  }
}

// ---------------------------------------------------------------------------
// k_mm2: M_bf16[n*4+a] = relu( relu(U1[x[n]] + U2c[a] + B[n]) @ Wu2 + bu2 )
// Same tiling; fp32 FMA, bf16 store (storage quantization only).
// ---------------------------------------------------------------------------
__global__ __launch_bounds__(256, 4) void k_mm2(const float* __restrict__ B_,
                                                const int* __restrict__ x,
                                                const float* __restrict__ U1,
                                                const float* __restrict__ U2c,
                                                const float* __restrict__ Wu2,
                                                const float* __restrict__ bu2,
                                                __hip_bfloat16* __restrict__ M) {
  __shared__ float Hs[64][132];
  __shared__ int xs[16];
  int t = threadIdx.x;
  int nbase = blockIdx.x * 16;
  if (t < 16) xs[t] = x[nbase + t];
  __syncthreads();
#pragma unroll
  for (int j = 0; j < 8; j++) {
    int idx = j * 256 + t;
    int rr = idx >> 5;            // local row = nl*4 + a
    int kq = idx & 31;
    int nl = rr >> 2, a = rr & 3;
    float4 u1 = *(const float4*)&U1[xs[nl] * 128 + kq * 4];
    float4 bb = *(const float4*)&B_[(nbase + nl) * 128 + kq * 4];
    float4 u2 = *(const float4*)&U2c[a * 128 + kq * 4];
    float4 h;
    h.x = u1.x + bb.x + u2.x; h.y = u1.y + bb.y + u2.y;
    h.z = u1.z + bb.z + u2.z; h.w = u1.w + bb.w + u2.w;
    h.x = h.x > 0.f ? h.x : 0.f; h.y = h.y > 0.f ? h.y : 0.f;
    h.z = h.z > 0.f ? h.z : 0.f; h.w = h.w > 0.f ? h.w : 0.f;
    *(float4*)&Hs[rr][kq * 4] = h;
  }
  __syncthreads();
  int r0 = (t >> 4) * 4;
  int c0 = (t & 15) * 8;
  float acc[4][8];
  {
    float4 bias0 = *(const float4*)&bu2[c0];
    float4 bias1 = *(const float4*)&bu2[c0 + 4];
#pragma unroll
    for (int r = 0; r < 4; r++) {
      acc[r][0] = bias0.x; acc[r][1] = bias0.y; acc[r][2] = bias0.z; acc[r][3] = bias0.w;
      acc[r][4] = bias1.x; acc[r][5] = bias1.y; acc[r][6] = bias1.z; acc[r][7] = bias1.w;
    }
  }
#pragma unroll 2
  for (int kq = 0; kq < 32; kq++) {
    const int k = kq * 4;
    float h0[4], h1[4], h2[4], h3[4];
    *(float4*)h0 = *(const float4*)&Hs[r0][k];
    *(float4*)h1 = *(const float4*)&Hs[r0 + 1][k];
    *(float4*)h2 = *(const float4*)&Hs[r0 + 2][k];
    *(float4*)h3 = *(const float4*)&Hs[r0 + 3][k];
#pragma unroll
    for (int i = 0; i < 4; i++) {
      float w[8];
      *(float4*)&w[0] = *(const float4*)&Wu2[(k + i) * 128 + c0];
      *(float4*)&w[4] = *(const float4*)&Wu2[(k + i) * 128 + c0 + 4];
      float hv[4] = {h0[i], h1[i], h2[i], h3[i]};
#pragma unroll
      for (int r = 0; r < 4; r++)
#pragma unroll
        for (int j = 0; j < 8; j++) acc[r][j] += hv[r] * w[j];
    }
  }
  int rowbase = nbase * 4;
#pragma unroll
  for (int r = 0; r < 4; r++) {
    union { __hip_bfloat16 b[8]; int4 v; } u;
#pragma unroll
    for (int j = 0; j < 8; j++) {
      float vv = acc[r][j] > 0.f ? acc[r][j] : 0.f;
      u.b[j] = __float2bfloat16(vv);
    }
    *(int4*)&M[(rowbase + r0 + r) * 128 + c0] = u.v;
  }
}

// ---------------------------------------------------------------------------
// mol_state[batch[n]] += node_state[n]
// ---------------------------------------------------------------------------
__global__ void k_mol(const float* __restrict__ node,
                      const int* __restrict__ batch,
                      float* __restrict__ mol) {
  int idx = blockIdx.x * 256 + threadIdx.x;
  int n = idx >> 7;
  int c = idx & 127;
  atomicAdd(&mol[batch[n] * 128 + c], node[idx]);
}

// ---------------------------------------------------------------------------
// out[m] = relu(mol[m] @ Wr1 + br1) @ Wr2 + br2
// ---------------------------------------------------------------------------
__global__ __launch_bounds__(256) void k_readout(const float* __restrict__ mol,
                                                 const float* __restrict__ Wr1,
                                                 const float* __restrict__ br1,
                                                 const float* __restrict__ Wr2,
                                                 const float* __restrict__ br2,
                                                 float* __restrict__ out) {
  int m = blockIdx.x;
  __shared__ float ms[128];
  __shared__ float red[256];
  int t = threadIdx.x;
  if (t < 128) ms[t] = mol[m * 128 + t];
  __syncthreads();
  float part = 0.f;
#pragma unroll
  for (int jj = 0; jj < 2; jj++) {
    int j = t + jj * 256;
    float acc = br1[j];
#pragma unroll
    for (int k = 0; k < 128; k += 4) {
      float4 m4 = *(const float4*)&ms[k];
      acc += m4.x * Wr1[k * 512 + j] + m4.y * Wr1[(k + 1) * 512 + j] +
             m4.z * Wr1[(k + 2) * 512 + j] + m4.w * Wr1[(k + 3) * 512 + j];
    }
    acc = acc > 0.f ? acc : 0.f;
    part += acc * Wr2[j];
  }
  red[t] = part;
  __syncthreads();
  for (int s = 128; s > 0; s >>= 1) {
    if (t < s) red[t] += red[t + s];
    __syncthreads();
  }
  if (t == 0) out[m] = red[0] + br2[0];
}

// ---------------------------------------------------------------------------
extern "C" void kernel_launch(void* const* d_in, const int* in_sizes, int n_in,
                              void* d_out, int out_size, void* d_ws, size_t ws_size,
                              hipStream_t stream) {
  const int* x        = (const int*)d_in[0];
  const int* eattr    = (const int*)d_in[1];
  const int* eidx     = (const int*)d_in[2];
  const int* batch    = (const int*)d_in[3];
  const float* atom_table = (const float*)d_in[4];
  const float* bond_table = (const float*)d_in[5];
  const float* Wi  = (const float*)d_in[6];
  const float* bi  = (const float*)d_in[7];
  const float* Wu1 = (const float*)d_in[8];
  const float* bu1 = (const float*)d_in[9];
  const float* Wu2 = (const float*)d_in[10];
  const float* bu2 = (const float*)d_in[11];
  const float* Wr1 = (const float*)d_in[12];
  const float* br1 = (const float*)d_in[13];
  const float* Wr2 = (const float*)d_in[14];
  const float* br2 = (const float*)d_in[15];
  float* out = (float*)d_out;

  char* ws = (char*)d_ws;
  __hip_bfloat16* M = (__hip_bfloat16*)(ws);       //  51,200,000 B (bf16 now)
  float* A      = (float*)(ws + 102400000);        //  25,600,000 B
  float* B      = (float*)(ws + 128000000);        //  25,600,000 B
  int*   csr    = (int*)  (ws + 153600000);        //   3,200,000 B
  int*   rowptr = (int*)  (ws + 156800000);        //     200,064 B
  float* T1     = (float*)(ws + 157000064);        //      60,928 B
  float* U1     = (float*)(ws + 157060992);        //      60,928 B
  float* T2c    = (float*)(ws + 157121920);        //       2,048 B
  float* U2c    = (float*)(ws + 157123968);        //       2,048 B
  float* TT     = (float*)(ws + 157126016);        //     243,712 B
  float* mol    = (float*)(ws + 157369728);        //   1,024,000 B
  // cnt/cursor alias B: only live before the first k_mm1 write to B.
  int*   cnt    = (int*)B;
  int*   cursor = (int*)(ws + 128000000 + 204800);

  hipMemsetAsync(cnt, 0, N_NODES * sizeof(int), stream);
  k_tables<<<123, 128, 0, stream>>>(atom_table, bond_table, Wi, bi, Wu1, bu1,
                                    T1, U1, T2c, U2c);
  k_tt<<<476, 128, 0, stream>>>(T1, T2c, TT);
  k_hist<<<N_EDGES / 256, 256, 0, stream>>>(eidx, cnt);
  k_scan<<<1, 1024, 0, stream>>>(cnt, rowptr, cursor);
  k_fill<<<N_EDGES / 256, 256, 0, stream>>>(eidx, eattr, cursor, csr);

  k_gather0<<<N_NODES / 4, 256, 0, stream>>>(rowptr, csr, x, TT, A);

  for (int p = 0; p < 4; p++) {
    k_mm1<<<(N_NODES + 63) / 64, 256, 0, stream>>>(A, Wu1, B);
    k_mm2<<<(4 * N_NODES) / 64, 256, 0, stream>>>(B, x, U1, U2c, Wu2, bu2, M);
    k_gather<<<N_NODES / 4, 256, 0, stream>>>(rowptr, csr, M, A);
  }

  hipMemsetAsync(mol, 0, NUM_MOL * 128 * sizeof(float), stream);
  k_mol<<<(N_NODES * 128) / 256, 256, 0, stream>>>(A, batch, mol);
  k_readout<<<NUM_MOL, 256, 0, stream>>>(mol, Wr1, br1, Wr2, br2, out);
}